// Round 6
// baseline (368.312 us; speedup 1.0000x reference)
//
#include <hip/hip_runtime.h>
#include <hip/hip_bf16.h>
#include <stdint.h>

#define NH 16
#define HD 64
#define DM 1024
#define NB 4
#define SEQ 1024
#define NTOK (NB*SEQ)
#define SCALE 0.125f

typedef __bf16 bf16_t;
typedef __bf16 bf16x8 __attribute__((ext_vector_type(8)));
typedef __bf16 bf16x4 __attribute__((ext_vector_type(4)));
typedef float f32x4 __attribute__((ext_vector_type(4)));

typedef __attribute__((address_space(3))) unsigned char lds_byte;
typedef __attribute__((address_space(1))) const unsigned char gbl_byte;

__device__ __forceinline__ void glds16(const void* g, void* l){
  __builtin_amdgcn_global_load_lds((gbl_byte*)g, (lds_byte*)l, 16, 0, 0);
}

// ---------------- fp32 -> bf16 convert (hidden_states) ----------------
__global__ void cvt_hs_kernel(const float* __restrict__ in, bf16_t* __restrict__ out, int n4){
  int i = blockIdx.x*256 + threadIdx.x;
  if (i >= n4) return;
  f32x4 v = ((const f32x4*)in)[i];
  bf16x4 o;
  o[0]=(bf16_t)v[0]; o[1]=(bf16_t)v[1]; o[2]=(bf16_t)v[2]; o[3]=(bf16_t)v[3];
  ((bf16x4*)out)[i] = o;
}

// ------------- W transpose + convert: Wt[n][k] = W[k][n] (bf16) -------------
__global__ void cvt_wt_kernel(const float* __restrict__ Wq, const float* __restrict__ Wk,
                              const float* __restrict__ Wv, bf16_t* __restrict__ outbase){
  __shared__ float tile[32][33];
  const float* W = blockIdx.z==0 ? Wq : (blockIdx.z==1 ? Wk : Wv);
  bf16_t* Wt = outbase + (size_t)blockIdx.z * DM * DM;
  int k0 = blockIdx.x*32, n0 = blockIdx.y*32;
  #pragma unroll
  for (int i=0;i<4;i++){
    int r = threadIdx.y + i*8;
    tile[r][threadIdx.x] = W[(size_t)(k0+r)*DM + n0 + threadIdx.x];
  }
  __syncthreads();
  #pragma unroll
  for (int i=0;i<4;i++){
    int r = threadIdx.y + i*8;
    Wt[(size_t)(n0+r)*DM + k0 + threadIdx.x] = (bf16_t)tile[threadIdx.x][r];
  }
}

// ---------------- QKV GEMM: bf16 MFMA, LDS-staged coalesced epilogue ----------------
// Q,K,V -> [bh][seq][hd] bf16 (V transposed by v_tr_kernel afterwards)
__global__ __launch_bounds__(256)
void qkv_gemm_kernel(const bf16_t* __restrict__ Ag, const bf16_t* __restrict__ Wtb,
                     const float* __restrict__ bq, const float* __restrict__ bk, const float* __restrict__ bv,
                     bf16_t* __restrict__ Qb, bf16_t* __restrict__ Kb, bf16_t* __restrict__ Vb)
{
  __shared__ __align__(16) bf16_t smem[2*128*64];   // Asm | Bsm ; aliased as 128x128 Csm
  bf16_t* Asm = smem;
  bf16_t* Bsm = smem + 128*64;
  bf16_t* Csm = smem;
  const int z = blockIdx.z;
  const bf16_t* Btg = Wtb + (size_t)z*DM*DM;
  const float* bias = (z==0)?bq:((z==1)?bk:bv);
  bf16_t* dst = (z==0)?Qb:((z==1)?Kb:Vb);
  const int m0 = blockIdx.x*128, n0 = blockIdx.y*128;
  const int tid = threadIdx.x, lane = tid&63, w = tid>>6;
  const int wr = w>>1, wc = w&1;
  const int lr = lane&15, hk = (lane>>4)<<3;

  f32x4 acc[4][4];
  #pragma unroll
  for (int a=0;a<4;a++)
    #pragma unroll
    for (int c=0;c<4;c++)
      acc[a][c] = (f32x4){0.f,0.f,0.f,0.f};

  for (int k0=0; k0<DM; k0+=64){
    #pragma unroll
    for (int i=0;i<4;i++){
      int cb = (i<<8) + (tid & 448);       // wave-uniform chunk base
      int flat = cb + lane;
      int row = flat>>3, kc = (flat&7)<<3;
      glds16(&Ag [(size_t)(m0+row)*DM + k0 + kc], &Asm[cb<<3]);
      glds16(&Btg[(size_t)(n0+row)*DM + k0 + kc], &Bsm[cb<<3]);
    }
    __syncthreads();
    #pragma unroll
    for (int kk=0;kk<2;kk++){
      bf16x8 af[4], bfv[4];
      #pragma unroll
      for (int mf=0;mf<4;mf++)
        af[mf] = *(const bf16x8*)&Asm[((wr*64 + mf*16 + lr)<<6) + (kk<<5) + hk];
      #pragma unroll
      for (int nf=0;nf<4;nf++)
        bfv[nf] = *(const bf16x8*)&Bsm[((wc*64 + nf*16 + lr)<<6) + (kk<<5) + hk];
      #pragma unroll
      for (int mf=0;mf<4;mf++)
        #pragma unroll
        for (int nf=0;nf<4;nf++)
          acc[mf][nf] = __builtin_amdgcn_mfma_f32_16x16x32_bf16(af[mf], bfv[nf], acc[mf][nf], 0, 0, 0);
    }
    __syncthreads();
  }

  // ---- epilogue: acc(+bias) -> Csm, then coalesced 128B-row stores ----
  const int q4 = (lane>>4)<<2;
  #pragma unroll
  for (int mf=0;mf<4;mf++){
    #pragma unroll
    for (int nf=0;nf<4;nf++){
      int col = wc*64 + nf*16 + lr;
      float bsv = bias[n0 + col];
      #pragma unroll
      for (int j=0;j<4;j++)
        Csm[(wr*64 + mf*16 + q4 + j)*128 + col] = (bf16_t)(acc[mf][nf][j] + bsv);
    }
  }
  __syncthreads();
  {
    int row = tid>>1, half = tid&1;             // 128 rows x 2 halves (64 cols = 128B)
    int gm = m0 + row, bb = gm>>10, sq = gm&1023;
    int hh = (n0 + half*64)>>6;
    const bf16x8* src = (const bf16x8*)&Csm[row*128 + half*64];
    bf16x8* d = (bf16x8*)&dst[(((size_t)bb*NH + hh)*SEQ + sq)*HD];
    #pragma unroll
    for (int c=0;c<8;c++) d[c] = src[c];
  }
}

// ---------------- V transpose: Vt[bh][hd][sq] = Vb[bh][sq][hd] ----------------
__global__ __launch_bounds__(256)
void v_tr_kernel(const bf16_t* __restrict__ Vb, bf16_t* __restrict__ Vt){
  __shared__ __align__(16) bf16_t T[64*64];   // granule-swizzled 64x64 tile
  const int bh = blockIdx.y, sq0 = blockIdx.x*64;
  const int t = threadIdx.x;
  const bf16_t* src = Vb + ((size_t)bh*SEQ + sq0)*HD;
  #pragma unroll
  for (int i=0;i<2;i++){
    int flat = i*256 + t;                     // 0..511
    int r = flat>>3, ch = flat&7;
    bf16x8 v = *(const bf16x8*)&src[r*HD + ch*8];
    *(bf16x8*)((char*)T + r*128 + ((ch ^ (r&7))*16)) = v;
  }
  __syncthreads();
  const int hd = t>>2, part = t&3;            // hd 0..63, sq part*16..+15
  bf16_t tmp[16];
  #pragma unroll
  for (int s=0;s<16;s++){
    int sq = part*16 + s;
    tmp[s] = *(const bf16_t*)((char*)T + sq*128 + (((hd>>3) ^ (sq&7))*16) + (hd&7)*2);
  }
  bf16_t* d = Vt + ((size_t)bh*HD + hd)*SEQ + sq0 + part*16;
  *(bf16x8*)&d[0] = *(const bf16x8*)&tmp[0];
  *(bf16x8*)&d[8] = *(const bf16x8*)&tmp[8];
}

// ---------------- interleaved 4-row wave reductions ----------------
__device__ __forceinline__ void red4sum(float v[4]){
  #pragma unroll
  for (int m=32;m>=1;m>>=1){
    float t0=__shfl_xor(v[0],m,64), t1=__shfl_xor(v[1],m,64);
    float t2=__shfl_xor(v[2],m,64), t3=__shfl_xor(v[3],m,64);
    v[0]+=t0; v[1]+=t1; v[2]+=t2; v[3]+=t3;
  }
}
__device__ __forceinline__ void red4max(float v[4]){
  #pragma unroll
  for (int m=32;m>=1;m>>=1){
    float t0=__shfl_xor(v[0],m,64), t1=__shfl_xor(v[1],m,64);
    float t2=__shfl_xor(v[2],m,64), t3=__shfl_xor(v[3],m,64);
    v[0]=fmaxf(v[0],t0); v[1]=fmaxf(v[1],t1); v[2]=fmaxf(v[2],t2); v[3]=fmaxf(v[3],t3);
  }
}

// ---------------- fused MFMA attention, 64KB LDS, XCD-aware block mapping ----------------
// NOTE: plain __launch_bounds__(512). The ",4" min-occupancy arg capped VGPR at 64 and
// spilled z[4][16] to scratch: 192MB phantom HBM writes (R3/R5). R2 proof: (512) -> 88 VGPR, 16MB.
__global__ __launch_bounds__(512)
void attn_mfma2_kernel(const bf16_t* __restrict__ Qg, const bf16_t* __restrict__ Kg,
                       const bf16_t* __restrict__ Vt, const float* __restrict__ maskg,
                       float* __restrict__ outg)
{
  __shared__ __align__(16) bf16_t Sb[32*1024];   // 64KB: swizzled scores -> weights -> out stage
  char* Sbb = (char*)Sb;

  // XCD-chunked mapping: all 32 q-tiles of a head on one XCD (flat%8 round-robin assumption)
  const int flat = blockIdx.x;
  const int xcd = flat & 7, jj = flat >> 3;
  const int bh = ((jj>>5)<<3) | xcd;
  const int row0 = (jj&31)*32;
  const int b = bh>>4, h = bh&15;
  const int tid = threadIdx.x, lane = tid&63, w = tid>>6;
  const int ln = lane&15, hi4 = lane>>4;
  const size_t hoff = (size_t)bh*SEQ*HD;
  const int kbase = w*128;

  // Q fragments (B-operand): rows q = mt*16+ln, k = kt*32 + hi4*8
  bf16x8 qf[2][2];
  #pragma unroll
  for (int mt=0; mt<2; ++mt)
    #pragma unroll
    for (int kt=0; kt<2; ++kt)
      qf[mt][kt] = *(const bf16x8*)&Qg[hoff + (size_t)(row0 + mt*16 + ln)*HD + kt*32 + hi4*8];

  // ---- QK^T (swapped: A=K) -> swizzled bf16 scores ----
  #pragma unroll
  for (int nt=0; nt<8; ++nt){
    const int krow = kbase + nt*16;
    bf16x8 kf0 = *(const bf16x8*)&Kg[hoff + (size_t)(krow+ln)*HD +  0 + hi4*8];
    bf16x8 kf1 = *(const bf16x8*)&Kg[hoff + (size_t)(krow+ln)*HD + 32 + hi4*8];
    f32x4 mv = *(const f32x4*)&maskg[(size_t)b*SEQ + krow + hi4*4];
    #pragma unroll
    for (int mt=0; mt<2; ++mt){
      f32x4 acc = (f32x4){0.f,0.f,0.f,0.f};
      acc = __builtin_amdgcn_mfma_f32_16x16x32_bf16(kf0, qf[mt][0], acc, 0,0,0);
      acc = __builtin_amdgcn_mfma_f32_16x16x32_bf16(kf1, qf[mt][1], acc, 0,0,0);
      bf16x4 pk;
      #pragma unroll
      for (int j=0;j<4;++j)
        pk[j] = (bf16_t)fmaxf(fmaf(acc[j], SCALE, mv[j]), -10000.f);
      const int q = mt*16 + ln;
      const int g = (krow + hi4*4) >> 3;
      const int gp = g ^ ln;
      *(bf16x4*)(Sbb + q*2048 + gp*16 + (hi4&1)*8) = pk;
    }
  }
  __syncthreads();

  // ---- pull 4 rows to registers ----
  float z[4][16];
  const int qr = w*4;
  #pragma unroll
  for (int r=0;r<4;++r){
    const int q = qr + r;
    #pragma unroll
    for (int i=0;i<4;++i){
      const int gp = (i*32 + (lane>>1)) ^ (q&15);
      bf16x4 v4 = *(const bf16x4*)(Sbb + q*2048 + gp*16 + (lane&1)*8);
      z[r][i*4+0]=(float)v4[0]; z[r][i*4+1]=(float)v4[1];
      z[r][i*4+2]=(float)v4[2]; z[r][i*4+3]=(float)v4[3];
    }
  }
  __syncthreads();

  // ---- row max ----
  float mx[4];
  #pragma unroll
  for (int r=0;r<4;++r){
    float m = z[r][0];
    #pragma unroll
    for (int i=1;i<16;++i) m = fmaxf(m, z[r][i]);
    mx[r] = m;
  }
  red4max(mx);

  if ((h&1)==0){
    // ---- sparsemax: 8 bisection + 3 Michelot ----
    float lo[4], hi_[4];
    #pragma unroll
    for (int r=0;r<4;++r){ lo[r]=mx[r]-1.0f; hi_[r]=mx[r]; }
    for (int it=0; it<8; ++it){
      float mid[4], g4[4];
      #pragma unroll
      for (int r=0;r<4;++r){
        mid[r] = 0.5f*(lo[r]+hi_[r]);
        float g = 0.f;
        #pragma unroll
        for (int i=0;i<16;++i) g += fmaxf(z[r][i]-mid[r], 0.f);
        g4[r] = g;
      }
      red4sum(g4);
      #pragma unroll
      for (int r=0;r<4;++r){
        if (g4[r] >= 1.0f) lo[r] = mid[r]; else hi_[r] = mid[r];
      }
    }
    float tau[4];
    #pragma unroll
    for (int r=0;r<4;++r) tau[r] = lo[r];
    for (int it=0; it<3; ++it){
      float cnt[4], sm[4];
      #pragma unroll
      for (int r=0;r<4;++r){
        float c=0.f, s=0.f;
        #pragma unroll
        for (int i=0;i<16;++i){
          bool in = z[r][i] > tau[r];
          c += in ? 1.0f : 0.0f;
          s += in ? z[r][i] : 0.0f;
        }
        cnt[r]=c; sm[r]=s;
      }
      red4sum(cnt); red4sum(sm);
      #pragma unroll
      for (int r=0;r<4;++r) tau[r] = (sm[r]-1.0f)/cnt[r];
    }
    #pragma unroll
    for (int r=0;r<4;++r)
      #pragma unroll
      for (int i=0;i<16;++i) z[r][i] = fmaxf(z[r][i]-tau[r], 0.f);
  } else {
    // ---- softmax ----
    float sm[4];
    #pragma unroll
    for (int r=0;r<4;++r){
      float s = 0.f;
      #pragma unroll
      for (int i=0;i<16;++i){ z[r][i] = __expf(z[r][i]-mx[r]); s += z[r][i]; }
      sm[r] = s;
    }
    red4sum(sm);
    #pragma unroll
    for (int r=0;r<4;++r){
      float inv = 1.0f/sm[r];
      #pragma unroll
      for (int i=0;i<16;++i) z[r][i] *= inv;
    }
  }

  // ---- store weights bf16, same swizzle ----
  #pragma unroll
  for (int r=0;r<4;++r){
    const int q = qr + r;
    #pragma unroll
    for (int i=0;i<4;++i){
      bf16x4 pk;
      pk[0]=(bf16_t)z[r][i*4+0]; pk[1]=(bf16_t)z[r][i*4+1];
      pk[2]=(bf16_t)z[r][i*4+2]; pk[3]=(bf16_t)z[r][i*4+3];
      const int gp = (i*32 + (lane>>1)) ^ (q&15);
      *(bf16x4*)(Sbb + q*2048 + gp*16 + (lane&1)*8) = pk;
    }
  }
  __syncthreads();

  // ---- PV: wave -> (q-tile, hd-tile), full k=1024 ----
  const int mt = w>>2, hd0 = (w&3)*16;
  const bf16_t* vrow = Vt + (size_t)bh*HD*SEQ + (size_t)(hd0+ln)*SEQ;
  const char* wrow = Sbb + (mt*16+ln)*2048;
  f32x4 o0 = (f32x4){0.f,0.f,0.f,0.f}, o1 = (f32x4){0.f,0.f,0.f,0.f};
  #pragma unroll
  for (int kt=0; kt<32; kt+=2){
    bf16x8 wa0 = *(const bf16x8*)(wrow + ((((kt+0)*4+hi4) ^ ln)<<4));
    bf16x8 vb0 = *(const bf16x8*)&vrow[(kt+0)*32 + hi4*8];
    o0 = __builtin_amdgcn_mfma_f32_16x16x32_bf16(wa0, vb0, o0, 0,0,0);
    bf16x8 wa1 = *(const bf16x8*)(wrow + ((((kt+1)*4+hi4) ^ ln)<<4));
    bf16x8 vb1 = *(const bf16x8*)&vrow[(kt+1)*32 + hi4*8];
    o1 = __builtin_amdgcn_mfma_f32_16x16x32_bf16(wa1, vb1, o1, 0,0,0);
  }
  o0 += o1;

  // ---- stage output tile in LDS, coalesced f32x4 writes ----
  __syncthreads();                       // all PV weight reads done
  float* Ob = (float*)Sbb;               // 32x64 fp32 = 8KB
  #pragma unroll
  for (int j=0;j<4;++j)
    Ob[(mt*16 + hi4*4 + j)*64 + hd0 + ln] = o0[j];
  __syncthreads();
  {
    int rr = tid>>4, c4 = (tid&15)<<2;
    *(f32x4*)&outg[(size_t)(b*SEQ + row0 + rr)*DM + h*64 + c4] = *(const f32x4*)&Ob[rr*64 + c4];
  }
}

// ---------------- launch ----------------
extern "C" void kernel_launch(void* const* d_in, const int* in_sizes, int n_in,
                              void* d_out, int out_size, void* d_ws, size_t ws_size,
                              hipStream_t stream)
{
  const float* hs   = (const float*)d_in[0];
  const float* Wq   = (const float*)d_in[1];
  const float* bq   = (const float*)d_in[2];
  const float* Wk   = (const float*)d_in[3];
  const float* bk   = (const float*)d_in[4];
  const float* Wv   = (const float*)d_in[5];
  const float* bv   = (const float*)d_in[6];
  const float* mask = (const float*)d_in[7];
  float* out = (float*)d_out;

  char* ws = (char*)d_ws;
  bf16_t* hsb = (bf16_t*)ws;                          // 8 MB (dead after gemm)
  bf16_t* Wt  = (bf16_t*)(ws + (size_t)( 8u<<20));    // 6 MB
  bf16_t* Qb  = (bf16_t*)(ws + (size_t)(14u<<20));    // 8 MB each
  bf16_t* Kb  = (bf16_t*)(ws + (size_t)(22u<<20));
  bf16_t* Vb  = (bf16_t*)(ws + (size_t)(30u<<20));
  bf16_t* Vt  = hsb;                                  // alias: hsb dead before v_tr

  cvt_hs_kernel<<<(NTOK*DM/4 + 255)/256, 256, 0, stream>>>(hs, hsb, NTOK*DM/4);
  cvt_wt_kernel<<<dim3(32,32,3), dim3(32,8), 0, stream>>>(Wq, Wk, Wv, Wt);
  qkv_gemm_kernel<<<dim3(32,8,3), 256, 0, stream>>>(hsb, Wt, bq, bk, bv, Qb, Kb, Vb);
  v_tr_kernel<<<dim3(16,64), 256, 0, stream>>>(Vb, Vt);
  attn_mfma2_kernel<<<2048, 512, 0, stream>>>(Qb, Kb, Vt, mask, out);
}

// Round 7
// 315.153 us; speedup vs baseline: 1.1687x; 1.1687x over previous
//
#include <hip/hip_runtime.h>
#include <hip/hip_bf16.h>
#include <stdint.h>

#define NH 16
#define HD 64
#define DM 1024
#define NB 4
#define SEQ 1024
#define NTOK (NB*SEQ)
#define SCALE 0.125f

typedef __bf16 bf16_t;
typedef __bf16 bf16x8 __attribute__((ext_vector_type(8)));
typedef __bf16 bf16x4 __attribute__((ext_vector_type(4)));
typedef float f32x4 __attribute__((ext_vector_type(4)));

typedef __attribute__((address_space(3))) unsigned char lds_byte;
typedef __attribute__((address_space(1))) const unsigned char gbl_byte;

__device__ __forceinline__ void glds16(const void* g, void* l){
  __builtin_amdgcn_global_load_lds((gbl_byte*)g, (lds_byte*)l, 16, 0, 0);
}

// ---------------- fp32 -> bf16 convert (hidden_states) ----------------
__global__ void cvt_hs_kernel(const float* __restrict__ in, bf16_t* __restrict__ out, int n4){
  int i = blockIdx.x*256 + threadIdx.x;
  if (i >= n4) return;
  f32x4 v = ((const f32x4*)in)[i];
  bf16x4 o;
  o[0]=(bf16_t)v[0]; o[1]=(bf16_t)v[1]; o[2]=(bf16_t)v[2]; o[3]=(bf16_t)v[3];
  ((bf16x4*)out)[i] = o;
}

// ------------- W transpose + convert: Wt[n][k] = W[k][n] (bf16) -------------
__global__ void cvt_wt_kernel(const float* __restrict__ Wq, const float* __restrict__ Wk,
                              const float* __restrict__ Wv, bf16_t* __restrict__ outbase){
  __shared__ float tile[32][33];
  const float* W = blockIdx.z==0 ? Wq : (blockIdx.z==1 ? Wk : Wv);
  bf16_t* Wt = outbase + (size_t)blockIdx.z * DM * DM;
  int k0 = blockIdx.x*32, n0 = blockIdx.y*32;
  #pragma unroll
  for (int i=0;i<4;i++){
    int r = threadIdx.y + i*8;
    tile[r][threadIdx.x] = W[(size_t)(k0+r)*DM + n0 + threadIdx.x];
  }
  __syncthreads();
  #pragma unroll
  for (int i=0;i<4;i++){
    int r = threadIdx.y + i*8;
    Wt[(size_t)(n0+r)*DM + k0 + threadIdx.x] = (bf16_t)tile[threadIdx.x][r];
  }
}

// ---------------- QKV GEMM: bf16 MFMA, LDS-staged coalesced epilogue ----------------
__global__ __launch_bounds__(256)
void qkv_gemm_kernel(const bf16_t* __restrict__ Ag, const bf16_t* __restrict__ Wtb,
                     const float* __restrict__ bq, const float* __restrict__ bk, const float* __restrict__ bv,
                     bf16_t* __restrict__ Qb, bf16_t* __restrict__ Kb, bf16_t* __restrict__ Vb)
{
  __shared__ __align__(16) bf16_t smem[2*128*64];   // Asm | Bsm ; aliased as 128x128 Csm
  bf16_t* Asm = smem;
  bf16_t* Bsm = smem + 128*64;
  bf16_t* Csm = smem;
  const int z = blockIdx.z;
  const bf16_t* Btg = Wtb + (size_t)z*DM*DM;
  const float* bias = (z==0)?bq:((z==1)?bk:bv);
  bf16_t* dst = (z==0)?Qb:((z==1)?Kb:Vb);
  const int m0 = blockIdx.x*128, n0 = blockIdx.y*128;
  const int tid = threadIdx.x, lane = tid&63, w = tid>>6;
  const int wr = w>>1, wc = w&1;
  const int lr = lane&15, hk = (lane>>4)<<3;

  f32x4 acc[4][4];
  #pragma unroll
  for (int a=0;a<4;a++)
    #pragma unroll
    for (int c=0;c<4;c++)
      acc[a][c] = (f32x4){0.f,0.f,0.f,0.f};

  for (int k0=0; k0<DM; k0+=64){
    #pragma unroll
    for (int i=0;i<4;i++){
      int cb = (i<<8) + (tid & 448);       // wave-uniform chunk base
      int flat = cb + lane;
      int row = flat>>3, kc = (flat&7)<<3;
      glds16(&Ag [(size_t)(m0+row)*DM + k0 + kc], &Asm[cb<<3]);
      glds16(&Btg[(size_t)(n0+row)*DM + k0 + kc], &Bsm[cb<<3]);
    }
    __syncthreads();
    #pragma unroll
    for (int kk=0;kk<2;kk++){
      bf16x8 af[4], bfv[4];
      #pragma unroll
      for (int mf=0;mf<4;mf++)
        af[mf] = *(const bf16x8*)&Asm[((wr*64 + mf*16 + lr)<<6) + (kk<<5) + hk];
      #pragma unroll
      for (int nf=0;nf<4;nf++)
        bfv[nf] = *(const bf16x8*)&Bsm[((wc*64 + nf*16 + lr)<<6) + (kk<<5) + hk];
      #pragma unroll
      for (int mf=0;mf<4;mf++)
        #pragma unroll
        for (int nf=0;nf<4;nf++)
          acc[mf][nf] = __builtin_amdgcn_mfma_f32_16x16x32_bf16(af[mf], bfv[nf], acc[mf][nf], 0, 0, 0);
    }
    __syncthreads();
  }

  const int q4 = (lane>>4)<<2;
  #pragma unroll
  for (int mf=0;mf<4;mf++){
    #pragma unroll
    for (int nf=0;nf<4;nf++){
      int col = wc*64 + nf*16 + lr;
      float bsv = bias[n0 + col];
      #pragma unroll
      for (int j=0;j<4;j++)
        Csm[(wr*64 + mf*16 + q4 + j)*128 + col] = (bf16_t)(acc[mf][nf][j] + bsv);
    }
  }
  __syncthreads();
  {
    int row = tid>>1, half = tid&1;             // 128 rows x 2 halves (64 cols = 128B)
    int gm = m0 + row, bb = gm>>10, sq = gm&1023;
    int hh = (n0 + half*64)>>6;
    const bf16x8* src = (const bf16x8*)&Csm[row*128 + half*64];
    bf16x8* d = (bf16x8*)&dst[(((size_t)bb*NH + hh)*SEQ + sq)*HD];
    #pragma unroll
    for (int c=0;c<8;c++) d[c] = src[c];
  }
}

// ---------------- V transpose: Vt[bh][hd][sq] = Vb[bh][sq][hd] ----------------
__global__ __launch_bounds__(256)
void v_tr_kernel(const bf16_t* __restrict__ Vb, bf16_t* __restrict__ Vt){
  __shared__ __align__(16) bf16_t T[64*64];   // granule-swizzled 64x64 tile
  const int bh = blockIdx.y, sq0 = blockIdx.x*64;
  const int t = threadIdx.x;
  const bf16_t* src = Vb + ((size_t)bh*SEQ + sq0)*HD;
  #pragma unroll
  for (int i=0;i<2;i++){
    int flat = i*256 + t;                     // 0..511
    int r = flat>>3, ch = flat&7;
    bf16x8 v = *(const bf16x8*)&src[r*HD + ch*8];
    *(bf16x8*)((char*)T + r*128 + ((ch ^ (r&7))*16)) = v;
  }
  __syncthreads();
  const int hd = t>>2, part = t&3;            // hd 0..63, sq part*16..+15
  bf16_t tmp[16];
  #pragma unroll
  for (int s=0;s<16;s++){
    int sq = part*16 + s;
    tmp[s] = *(const bf16_t*)((char*)T + sq*128 + (((hd>>3) ^ (sq&7))*16) + (hd&7)*2);
  }
  bf16_t* d = Vt + ((size_t)bh*HD + hd)*SEQ + sq0 + part*16;
  *(bf16x8*)&d[0] = *(const bf16x8*)&tmp[0];
  *(bf16x8*)&d[8] = *(const bf16x8*)&tmp[8];
}

// ---------------- interleaved wave reductions ----------------
__device__ __forceinline__ void red2sum(float v[2]){
  #pragma unroll
  for (int m=32;m>=1;m>>=1){
    float t0=__shfl_xor(v[0],m,64), t1=__shfl_xor(v[1],m,64);
    v[0]+=t0; v[1]+=t1;
  }
}
__device__ __forceinline__ void red2max(float v[2]){
  #pragma unroll
  for (int m=32;m>=1;m>>=1){
    float t0=__shfl_xor(v[0],m,64), t1=__shfl_xor(v[1],m,64);
    v[0]=fmaxf(v[0],t0); v[1]=fmaxf(v[1],t1);
  }
}
__device__ __forceinline__ void red4sum(float v[4]){
  #pragma unroll
  for (int m=32;m>=1;m>>=1){
    float t0=__shfl_xor(v[0],m,64), t1=__shfl_xor(v[1],m,64);
    float t2=__shfl_xor(v[2],m,64), t3=__shfl_xor(v[3],m,64);
    v[0]+=t0; v[1]+=t1; v[2]+=t2; v[3]+=t3;
  }
}

// ---------------- fused MFMA attention: 16-row blocks, 40KB LDS, 8 waves ----------------
// grid 4096. Phase 1: wave w -> S^T for keys [w*128,+128) x 16 q.
// Phase 2: wave w owns rows {2w,2w+1} (row-exclusive: no barrier between pull and wstore).
// Phase 3: wave w -> (k-half w>>2, hd-tile (w&3)*16), LDS pair-reduce.
__global__ __launch_bounds__(512)
void attn_mfma3_kernel(const bf16_t* __restrict__ Qg, const bf16_t* __restrict__ Kg,
                       const bf16_t* __restrict__ Vt, const float* __restrict__ maskg,
                       float* __restrict__ outg)
{
  __shared__ __align__(16) bf16_t Sb[20*1024];   // 32KB scores/weights + 8KB partials
  char* Sbb = (char*)Sb;
  float* Pacc = (float*)(Sbb + 32768);           // [2][16][64] f32

  // XCD-chunked: all 64 q-tiles of a head on one XCD
  const int flat = blockIdx.x;
  const int xcd = flat & 7, jj = flat >> 3;
  const int bh = ((jj>>6)<<3) | xcd;
  const int row0 = (jj&63)*16;
  const int b = bh>>4, h = bh&15;
  const int tid = threadIdx.x, lane = tid&63, w = tid>>6;
  const int ln = lane&15, hi4 = lane>>4;
  const size_t hoff = (size_t)bh*SEQ*HD;
  const int kbase = w*128;

  // Q fragments (B-operand): row q = ln, k = kt*32 + hi4*8
  bf16x8 qf0 = *(const bf16x8*)&Qg[hoff + (size_t)(row0 + ln)*HD +  0 + hi4*8];
  bf16x8 qf1 = *(const bf16x8*)&Qg[hoff + (size_t)(row0 + ln)*HD + 32 + hi4*8];

  // ---- QK^T (swapped: A=K) -> swizzled bf16 scores [16][1024] ----
  #pragma unroll
  for (int nt=0; nt<8; ++nt){
    const int krow = kbase + nt*16;
    bf16x8 kf0 = *(const bf16x8*)&Kg[hoff + (size_t)(krow+ln)*HD +  0 + hi4*8];
    bf16x8 kf1 = *(const bf16x8*)&Kg[hoff + (size_t)(krow+ln)*HD + 32 + hi4*8];
    f32x4 mv = *(const f32x4*)&maskg[(size_t)b*SEQ + krow + hi4*4];
    f32x4 acc = (f32x4){0.f,0.f,0.f,0.f};
    acc = __builtin_amdgcn_mfma_f32_16x16x32_bf16(kf0, qf0, acc, 0,0,0);
    acc = __builtin_amdgcn_mfma_f32_16x16x32_bf16(kf1, qf1, acc, 0,0,0);
    // lane holds q-row ln, keys krow + hi4*4 + j
    bf16x4 pk;
    #pragma unroll
    for (int j=0;j<4;++j)
      pk[j] = (bf16_t)fmaxf(fmaf(acc[j], SCALE, mv[j]), -10000.f);
    const int g = (krow + hi4*4) >> 3;      // granule 0..127
    const int gp = g ^ ln;                  // XOR swizzle
    *(bf16x4*)(Sbb + ln*2048 + gp*16 + (hi4&1)*8) = pk;
  }
  __syncthreads();

  // ---- pull 2 rows to registers: lane owns keys i*256 + (lane>>1)*8 + (lane&1)*4 + jj ----
  float z[2][16];
  #pragma unroll
  for (int r=0;r<2;++r){
    const int q = w*2 + r;
    #pragma unroll
    for (int i=0;i<4;++i){
      const int gp = (i*32 + (lane>>1)) ^ q;
      bf16x4 v4 = *(const bf16x4*)(Sbb + q*2048 + gp*16 + (lane&1)*8);
      z[r][i*4+0]=(float)v4[0]; z[r][i*4+1]=(float)v4[1];
      z[r][i*4+2]=(float)v4[2]; z[r][i*4+3]=(float)v4[3];
    }
  }
  // row-exclusive from here: no barrier needed until weights complete

  float mx[2];
  #pragma unroll
  for (int r=0;r<2;++r){
    float m = z[r][0];
    #pragma unroll
    for (int i=1;i<16;++i) m = fmaxf(m, z[r][i]);
    mx[r] = m;
  }
  red2max(mx);

  if ((h&1)==0){
    // ---- sparsemax: 8 bisection + 3 Michelot ----
    float lo[2], hi_[2];
    #pragma unroll
    for (int r=0;r<2;++r){ lo[r]=mx[r]-1.0f; hi_[r]=mx[r]; }
    for (int it=0; it<8; ++it){
      float g2[2];
      #pragma unroll
      for (int r=0;r<2;++r){
        float mid = 0.5f*(lo[r]+hi_[r]);
        float g = 0.f;
        #pragma unroll
        for (int i=0;i<16;++i) g += fmaxf(z[r][i]-mid, 0.f);
        g2[r] = g;
      }
      red2sum(g2);
      #pragma unroll
      for (int r=0;r<2;++r){
        float mid = 0.5f*(lo[r]+hi_[r]);
        if (g2[r] >= 1.0f) lo[r] = mid; else hi_[r] = mid;
      }
    }
    float tau[2] = {lo[0], lo[1]};
    for (int it=0; it<3; ++it){
      float cs[4];                       // cnt0, cnt1, sm0, sm1 in one chain
      #pragma unroll
      for (int r=0;r<2;++r){
        float c=0.f, s=0.f;
        #pragma unroll
        for (int i=0;i<16;++i){
          bool in = z[r][i] > tau[r];
          c += in ? 1.0f : 0.0f;
          s += in ? z[r][i] : 0.0f;
        }
        cs[r]=c; cs[2+r]=s;
      }
      red4sum(cs);
      #pragma unroll
      for (int r=0;r<2;++r) tau[r] = (cs[2+r]-1.0f)/cs[r];
    }
    #pragma unroll
    for (int r=0;r<2;++r)
      #pragma unroll
      for (int i=0;i<16;++i) z[r][i] = fmaxf(z[r][i]-tau[r], 0.f);
  } else {
    // ---- softmax ----
    float sm[2];
    #pragma unroll
    for (int r=0;r<2;++r){
      float s = 0.f;
      #pragma unroll
      for (int i=0;i<16;++i){ z[r][i] = __expf(z[r][i]-mx[r]); s += z[r][i]; }
      sm[r] = s;
    }
    red2sum(sm);
    #pragma unroll
    for (int r=0;r<2;++r){
      float inv = 1.0f/sm[r];
      #pragma unroll
      for (int i=0;i<16;++i) z[r][i] *= inv;
    }
  }

  // ---- store weights bf16, same swizzle (row-exclusive) ----
  #pragma unroll
  for (int r=0;r<2;++r){
    const int q = w*2 + r;
    #pragma unroll
    for (int i=0;i<4;++i){
      bf16x4 pk;
      pk[0]=(bf16_t)z[r][i*4+0]; pk[1]=(bf16_t)z[r][i*4+1];
      pk[2]=(bf16_t)z[r][i*4+2]; pk[3]=(bf16_t)z[r][i*4+3];
      const int gp = (i*32 + (lane>>1)) ^ q;
      *(bf16x4*)(Sbb + q*2048 + gp*16 + (lane&1)*8) = pk;
    }
  }
  __syncthreads();

  // ---- PV: wave -> (k-half kh, hd-tile nt), 16 MFMA; LDS pair-reduce ----
  const int kh = w>>2, nt = w&3;
  const bf16_t* vrow = Vt + (size_t)bh*HD*SEQ + (size_t)(nt*16+ln)*SEQ + kh*512;
  const char* wrow = Sbb + ln*2048;
  f32x4 o0 = (f32x4){0.f,0.f,0.f,0.f}, o1 = (f32x4){0.f,0.f,0.f,0.f};
  #pragma unroll
  for (int kt=0; kt<16; kt+=2){
    int g0 = kh*64 + (kt+0)*4 + hi4;
    bf16x8 wa0 = *(const bf16x8*)(wrow + ((g0 ^ ln)<<4));
    bf16x8 vb0 = *(const bf16x8*)&vrow[(kt+0)*32 + hi4*8];
    o0 = __builtin_amdgcn_mfma_f32_16x16x32_bf16(wa0, vb0, o0, 0,0,0);
    int g1 = kh*64 + (kt+1)*4 + hi4;
    bf16x8 wa1 = *(const bf16x8*)(wrow + ((g1 ^ ln)<<4));
    bf16x8 vb1 = *(const bf16x8*)&vrow[(kt+1)*32 + hi4*8];
    o1 = __builtin_amdgcn_mfma_f32_16x16x32_bf16(wa1, vb1, o1, 0,0,0);
  }
  o0 += o1;
  #pragma unroll
  for (int j=0;j<4;++j)
    Pacc[(kh*16 + hi4*4 + j)*64 + nt*16 + ln] = o0[j];
  __syncthreads();

  // ---- pair-reduce partials, coalesced store ----
  if (tid < 256){
    int q = tid>>4, c4 = (tid&15)<<2;
    f32x4 s = *(const f32x4*)&Pacc[q*64 + c4] + *(const f32x4*)&Pacc[(16+q)*64 + c4];
    *(f32x4*)&outg[(size_t)(b*SEQ + row0 + q)*DM + h*64 + c4] = s;
  }
}

// ---------------- launch ----------------
extern "C" void kernel_launch(void* const* d_in, const int* in_sizes, int n_in,
                              void* d_out, int out_size, void* d_ws, size_t ws_size,
                              hipStream_t stream)
{
  const float* hs   = (const float*)d_in[0];
  const float* Wq   = (const float*)d_in[1];
  const float* bq   = (const float*)d_in[2];
  const float* Wk   = (const float*)d_in[3];
  const float* bk   = (const float*)d_in[4];
  const float* Wv   = (const float*)d_in[5];
  const float* bv   = (const float*)d_in[6];
  const float* mask = (const float*)d_in[7];
  float* out = (float*)d_out;

  char* ws = (char*)d_ws;
  bf16_t* hsb = (bf16_t*)ws;                          // 8 MB (dead after gemm)
  bf16_t* Wt  = (bf16_t*)(ws + (size_t)( 8u<<20));    // 6 MB
  bf16_t* Qb  = (bf16_t*)(ws + (size_t)(14u<<20));    // 8 MB each
  bf16_t* Kb  = (bf16_t*)(ws + (size_t)(22u<<20));
  bf16_t* Vb  = (bf16_t*)(ws + (size_t)(30u<<20));
  bf16_t* Vt  = hsb;                                  // alias: hsb dead before v_tr

  cvt_hs_kernel<<<(NTOK*DM/4 + 255)/256, 256, 0, stream>>>(hs, hsb, NTOK*DM/4);
  cvt_wt_kernel<<<dim3(32,32,3), dim3(32,8), 0, stream>>>(Wq, Wk, Wv, Wt);
  qkv_gemm_kernel<<<dim3(32,8,3), 256, 0, stream>>>(hsb, Wt, bq, bk, bv, Qb, Kb, Vb);
  v_tr_kernel<<<dim3(16,64), 256, 0, stream>>>(Vb, Vt);
  attn_mfma3_kernel<<<4096, 512, 0, stream>>>(Qb, Kb, Vt, mask, out);
}